// Round 6
// baseline (860.439 us; speedup 1.0000x reference)
//
#include <hip/hip_runtime.h>

#define N_NODES 50000
#define N_EDGES 1600000
#define R_REL 8
#define G_GRAPHS 64
#define D_INF 128
#define HIDF 128
#define CLSF 10

#define S_SEG (N_NODES * R_REL)   // 400000 (dst, rel) segments

typedef __attribute__((ext_vector_type(8))) short short8;
typedef __attribute__((ext_vector_type(4))) float floatx4;

__device__ __forceinline__ unsigned short f2bf(float f) {
    unsigned int u = __float_as_uint(f);
    unsigned int r = (u + 0x7fffu + ((u >> 16) & 1u)) >> 16;   // RNE
    return (unsigned short)r;
}
__device__ __forceinline__ float bf2f(unsigned short h) {
    return __uint_as_float(((unsigned int)h) << 16);
}

// ---------------- count edges per (dst, rel) segment ----------------
__global__ void count_kernel(const int* __restrict__ dst, const int* __restrict__ et,
                             int* __restrict__ cnt) {
    int e = blockIdx.x * blockDim.x + threadIdx.x;
    if (e < N_EDGES) {
        atomicAdd(&cnt[dst[e] * R_REL + et[e]], 1);
    }
}

// ---------------- two-level exclusive scan over segment counts ----------------
#define SCAN_BLK 256
#define SCAN_ELEMS 1024
#define NB_SCAN ((S_SEG + SCAN_ELEMS - 1) / SCAN_ELEMS)   // 391

__global__ __launch_bounds__(SCAN_BLK) void scan1_kernel(const int* __restrict__ cnt,
                                                         int* __restrict__ off,
                                                         int* __restrict__ bsum) {
    __shared__ int sd[SCAN_BLK];
    int t = threadIdx.x;
    int base = blockIdx.x * SCAN_ELEMS + t * 4;
    int v[4];
    int tsum = 0;
#pragma unroll
    for (int j = 0; j < 4; j++) {
        v[j] = (base + j < S_SEG) ? cnt[base + j] : 0;
        tsum += v[j];
    }
    sd[t] = tsum;
    __syncthreads();
    for (int d = 1; d < SCAN_BLK; d <<= 1) {
        int x = (t >= d) ? sd[t - d] : 0;
        __syncthreads();
        sd[t] += x;
        __syncthreads();
    }
    int incl = sd[t];
    int run = incl - tsum;
#pragma unroll
    for (int j = 0; j < 4; j++) {
        if (base + j < S_SEG) off[base + j] = run;
        run += v[j];
    }
    if (t == SCAN_BLK - 1) bsum[blockIdx.x] = incl;
}

__global__ __launch_bounds__(512) void scan2_kernel(int* __restrict__ bsum) {
    __shared__ int sd[512];
    int t = threadIdx.x;
    int v = (t < NB_SCAN) ? bsum[t] : 0;
    sd[t] = v;
    __syncthreads();
    for (int d = 1; d < 512; d <<= 1) {
        int x = (t >= d) ? sd[t - d] : 0;
        __syncthreads();
        sd[t] += x;
        __syncthreads();
    }
    if (t < NB_SCAN) bsum[t] = sd[t] - v;
}

// make off[] absolute (add block prefix)
__global__ void absoff_kernel(int* __restrict__ off, const int* __restrict__ bsum) {
    int i = blockIdx.x * blockDim.x + threadIdx.x;
    if (i < S_SEG) off[i] += bsum[i >> 10];
}

// ---------------- bin edges into segment-sorted src list ----------------
__global__ void bin_kernel(const int* __restrict__ src,
                           const int* __restrict__ dst,
                           const int* __restrict__ et,
                           const int* __restrict__ off,
                           int* __restrict__ cursor,
                           int* __restrict__ sorted_src) {
    int e = blockIdx.x * blockDim.x + threadIdx.x;
    if (e < N_EDGES) {
        int seg = dst[e] * R_REL + et[e];
        int pos = atomicAdd(&cursor[seg], 1);
        sorted_src[off[seg] + pos] = src[e];
    }
}

// ---------------- convert x fp32 -> bf16 ----------------
__global__ void convx_kernel(const float* __restrict__ x, unsigned short* __restrict__ xb) {
    int idx = blockIdx.x * blockDim.x + threadIdx.x;
    if (idx < N_NODES * D_INF) xb[idx] = f2bf(x[idx]);
}

// ---------------- build transposed bf16 weights wtp[9][128][128]: [r][col][k] ----
// r<8: wtp[r][c][k] = W[r][k][c]; r==8: wtp[8][c][k] = root[k][c]
__global__ __launch_bounds__(256) void convw9_kernel(const float* __restrict__ W,
                                                     const float* __restrict__ root,
                                                     unsigned short* __restrict__ wtp) {
    __shared__ float t[16][17];
    int r = blockIdx.z;
    int k0 = blockIdx.x * 16, c0 = blockIdx.y * 16;
    int tx = threadIdx.x & 15, ty = threadIdx.x >> 4;
    const float* srcp = (r < 8) ? (W + (size_t)r * 128 * 128) : root;
    t[ty][tx] = srcp[(size_t)(k0 + ty) * 128 + c0 + tx];
    __syncthreads();
    wtp[(size_t)r * 16384 + (size_t)(c0 + ty) * 128 + k0 + tx] = f2bf(t[tx][ty]);
}

// ---------------- fused RGCN layer: gather-mean + MFMA GEMM + relu ----------------
// M-tile = 32 nodes, 256 threads (4 waves). For r in 0..8:
//   r<8 : A[s][ch] = mean of hin rows over segment (node0+s, r)   (gather, no atomics)
//   r==8: A[s][ch] = hin[node0+s][ch]                             (root pass)
//   B = wtp[r] (128 cols x 128 k), staged to LDS
//   acc += A x B^T via mfma_f32_16x16x32_bf16 (acc over r)
// epilogue: hout = relu(acc + bias) bf16.
#define APAD 136
__global__ __launch_bounds__(256) void rgcn_layer(
    const unsigned short* __restrict__ hin,      // [N,128] bf16
    const unsigned short* __restrict__ wtp,      // [9][128][128] bf16
    const float* __restrict__ bias,              // [128] fp32
    const int* __restrict__ segoff,              // [S_SEG] absolute edge offsets
    const int* __restrict__ segcnt,              // [S_SEG]
    const int* __restrict__ sorted_src,          // [E]
    unsigned short* __restrict__ hout)           // [N,128] bf16
{
    __shared__ __align__(16) unsigned short Alds[32][APAD];
    __shared__ __align__(16) unsigned short Blds[128][APAD];

    const int tx = threadIdx.x;
    const int wave = tx >> 6, lane = tx & 63;
    const int quad = lane >> 4, lq = lane & 15;
    const int hw = tx >> 5, l32 = tx & 31;
    const int node0 = blockIdx.x * 32;

    floatx4 acc[2][2];
#pragma unroll
    for (int i = 0; i < 2; i++)
#pragma unroll
        for (int j = 0; j < 2; j++) acc[i][j] = (floatx4){0.f, 0.f, 0.f, 0.f};

    for (int r = 0; r < 9; r++) {
        // ---- build A tile ----
        if (r < 8) {
#pragma unroll
            for (int q = 0; q < 4; q++) {
                int s = hw * 4 + q;            // node within tile, 0..31
                int node = node0 + s;
                if (node < N_NODES) {
                    int g = node * R_REL + r;
                    int n = segcnt[g];
                    int beg = segoff[g];
                    float a0 = 0.f, a1 = 0.f, a2 = 0.f, a3 = 0.f;
                    int i = 0;
                    for (; i + 4 <= n; i += 4) {
                        int i0 = sorted_src[beg + i + 0];
                        int i1 = sorted_src[beg + i + 1];
                        int i2 = sorted_src[beg + i + 2];
                        int i3 = sorted_src[beg + i + 3];
                        ushort4 v0 = *(const ushort4*)(hin + (size_t)i0 * HIDF + l32 * 4);
                        ushort4 v1 = *(const ushort4*)(hin + (size_t)i1 * HIDF + l32 * 4);
                        ushort4 v2 = *(const ushort4*)(hin + (size_t)i2 * HIDF + l32 * 4);
                        ushort4 v3 = *(const ushort4*)(hin + (size_t)i3 * HIDF + l32 * 4);
                        a0 += bf2f(v0.x) + bf2f(v1.x) + bf2f(v2.x) + bf2f(v3.x);
                        a1 += bf2f(v0.y) + bf2f(v1.y) + bf2f(v2.y) + bf2f(v3.y);
                        a2 += bf2f(v0.z) + bf2f(v1.z) + bf2f(v2.z) + bf2f(v3.z);
                        a3 += bf2f(v0.w) + bf2f(v1.w) + bf2f(v2.w) + bf2f(v3.w);
                    }
                    for (; i < n; i++) {
                        int ii = sorted_src[beg + i];
                        ushort4 v = *(const ushort4*)(hin + (size_t)ii * HIDF + l32 * 4);
                        a0 += bf2f(v.x); a1 += bf2f(v.y); a2 += bf2f(v.z); a3 += bf2f(v.w);
                    }
                    float inv = 1.0f / (float)max(n, 1);
                    ushort4 o;
                    o.x = f2bf(a0 * inv); o.y = f2bf(a1 * inv);
                    o.z = f2bf(a2 * inv); o.w = f2bf(a3 * inv);
                    *(ushort4*)(&Alds[s][l32 * 4]) = o;
                }
            }
        } else {
            // root pass: A = own features (zero for invalid tail rows)
#pragma unroll
            for (int p = 0; p < 2; p++) {
                int idx = tx + p * 256;        // 0..511
                int row = idx >> 4;            // 0..31
                int q = idx & 15;              // 16B chunk
                uint4 v = make_uint4(0u, 0u, 0u, 0u);
                int node = node0 + row;
                if (node < N_NODES)
                    v = *(const uint4*)(hin + (size_t)node * HIDF + q * 8);
                *(uint4*)(&Alds[row][q * 8]) = v;
            }
        }

        // ---- stage B = wtp[r] (128 x 128): 2 passes x 256 thr x 64B ----
        {
            const unsigned short* wr = wtp + (size_t)r * 16384;
#pragma unroll
            for (int p = 0; p < 2; p++) {
                int idx = tx + p * 256;        // 0..511
                int col = idx >> 2;            // 0..127
                int q = idx & 3;               // 64B (32-ushort) quarter
#pragma unroll
                for (int u = 0; u < 4; u++) {
                    uint4 v = *(const uint4*)(wr + (size_t)col * 128 + q * 32 + u * 8);
                    *(uint4*)(&Blds[col][q * 32 + u * 8]) = v;
                }
            }
        }
        __syncthreads();

        // ---- MFMA: 2 row frags x 2 col frags x 4 k-steps ----
#pragma unroll
        for (int kk = 0; kk < 4; kk++) {
            short8 af0 = *(const short8*)(&Alds[lq][kk * 32 + quad * 8]);
            short8 af1 = *(const short8*)(&Alds[16 + lq][kk * 32 + quad * 8]);
            short8 bq0 = *(const short8*)(&Blds[wave * 32 + lq][kk * 32 + quad * 8]);
            short8 bq1 = *(const short8*)(&Blds[wave * 32 + 16 + lq][kk * 32 + quad * 8]);
            acc[0][0] = __builtin_amdgcn_mfma_f32_16x16x32_bf16(af0, bq0, acc[0][0], 0, 0, 0);
            acc[0][1] = __builtin_amdgcn_mfma_f32_16x16x32_bf16(af0, bq1, acc[0][1], 0, 0, 0);
            acc[1][0] = __builtin_amdgcn_mfma_f32_16x16x32_bf16(af1, bq0, acc[1][0], 0, 0, 0);
            acc[1][1] = __builtin_amdgcn_mfma_f32_16x16x32_bf16(af1, bq1, acc[1][1], 0, 0, 0);
        }
        __syncthreads();
    }

    // ---- epilogue: C/D layout col=lane&15, row=quad*4+reg ----
#pragma unroll
    for (int i = 0; i < 2; i++) {
#pragma unroll
        for (int j = 0; j < 2; j++) {
            int col = wave * 32 + j * 16 + lq;
            float b = bias[col];
#pragma unroll
            for (int rg = 0; rg < 4; rg++) {
                int row = node0 + i * 16 + quad * 4 + rg;
                if (row < N_NODES) {
                    float v = fmaxf(acc[i][j][rg] + b, 0.0f);
                    hout[(size_t)row * HIDF + col] = f2bf(v);
                }
            }
        }
    }
}

// ---------------- global mean pool (batch sorted -> per-graph ranges) ----------
__global__ __launch_bounds__(256) void pool_kernel(const unsigned short* __restrict__ h,
                                                   const int* __restrict__ batch,
                                                   float* __restrict__ gmean) {
    int g = blockIdx.x;
    int lo, hi;
    {
        int l = 0, r = N_NODES;
        while (l < r) { int m = (l + r) >> 1; if (batch[m] < g) l = m + 1; else r = m; }
        lo = l;
        l = lo; r = N_NODES;
        while (l < r) { int m = (l + r) >> 1; if (batch[m] < g + 1) l = m + 1; else r = m; }
        hi = l;
    }
    int t = threadIdx.x;
    int c = t & 127;
    int half = t >> 7;
    float s = 0.0f;
    for (int n = lo + half; n < hi; n += 2) {
        s += bf2f(h[(size_t)n * HIDF + c]);
    }
    __shared__ float red[256];
    red[t] = s;
    __syncthreads();
    if (t < 128) {
        float tot = red[t] + red[t + 128];
        int n = hi - lo;
        gmean[g * HIDF + t] = tot / (float)max(n, 1);
    }
}

// ---------------- final linear ----------------
__global__ void final_kernel(const float* __restrict__ gmean,
                             const float* __restrict__ lin_w,  // [128, 10]
                             const float* __restrict__ lin_b,  // [10]
                             float* __restrict__ out) {        // [64, 10]
    __shared__ float gl[HIDF];
    int g = blockIdx.x;
    int hh = threadIdx.x;
    gl[hh] = gmean[g * HIDF + hh];
    __syncthreads();
    if (hh < CLSF) {
        float s = lin_b[hh];
#pragma unroll 16
        for (int d = 0; d < HIDF; d++) s += gl[d] * lin_w[d * CLSF + hh];
        out[g * CLSF + hh] = s;
    }
}

extern "C" void kernel_launch(void* const* d_in, const int* in_sizes, int n_in,
                              void* d_out, int out_size, void* d_ws, size_t ws_size,
                              hipStream_t stream) {
    const float* x     = (const float*)d_in[0];
    const int*   ei    = (const int*)d_in[1];
    const int*   et    = (const int*)d_in[2];
    const int*   batch = (const int*)d_in[3];
    const float* W1    = (const float*)d_in[4];
    const float* root1 = (const float*)d_in[5];
    const float* b1    = (const float*)d_in[6];
    const float* W2    = (const float*)d_in[7];
    const float* root2 = (const float*)d_in[8];
    const float* b2    = (const float*)d_in[9];
    const float* lin_w = (const float*)d_in[10];
    const float* lin_b = (const float*)d_in[11];
    float* out = (float*)d_out;

    const int* src = ei;            // edge_index[0]
    const int* dst = ei + N_EDGES;  // edge_index[1]

    char* ws = (char*)d_ws;
    unsigned short* xb  = (unsigned short*)ws; ws += (size_t)N_NODES * HIDF * 2;  // 12.8 MB
    unsigned short* h1  = (unsigned short*)ws; ws += (size_t)N_NODES * HIDF * 2;  // 12.8 MB
    unsigned short* h2  = (unsigned short*)ws; ws += (size_t)N_NODES * HIDF * 2;  // 12.8 MB
    unsigned short* wtp1 = (unsigned short*)ws; ws += (size_t)9 * 128 * 128 * 2;  // 288 KB
    unsigned short* wtp2 = (unsigned short*)ws; ws += (size_t)9 * 128 * 128 * 2;
    int*   cnt    = (int*)ws;   ws += (size_t)S_SEG * 4;
    int*   off    = (int*)ws;   ws += (size_t)S_SEG * 4;
    int*   bsum   = (int*)ws;   ws += 512 * 4;
    int*   cursor = (int*)ws;   ws += (size_t)S_SEG * 4;
    int*   sorted_src = (int*)ws; ws += (size_t)N_EDGES * 4;
    float* gmean  = (float*)ws; ws += (size_t)G_GRAPHS * HIDF * 4;

    hipMemsetAsync(cnt, 0, (size_t)S_SEG * 4, stream);
    hipMemsetAsync(cursor, 0, (size_t)S_SEG * 4, stream);

    // ---- counting sort of edges by (dst, rel) segment ----
    count_kernel<<<(N_EDGES + 255) / 256, 256, 0, stream>>>(dst, et, cnt);
    scan1_kernel<<<NB_SCAN, SCAN_BLK, 0, stream>>>(cnt, off, bsum);
    scan2_kernel<<<1, 512, 0, stream>>>(bsum);
    absoff_kernel<<<(S_SEG + 255) / 256, 256, 0, stream>>>(off, bsum);
    bin_kernel<<<(N_EDGES + 255) / 256, 256, 0, stream>>>(src, dst, et, off,
                                                          cursor, sorted_src);

    // ---- bf16 conversions ----
    convx_kernel<<<(N_NODES * D_INF + 255) / 256, 256, 0, stream>>>(x, xb);
    convw9_kernel<<<dim3(8, 8, 9), 256, 0, stream>>>(W1, root1, wtp1);
    convw9_kernel<<<dim3(8, 8, 9), 256, 0, stream>>>(W2, root2, wtp2);

    // ---- fused layers ----
    const int NBLK = (N_NODES + 31) / 32;   // 1563
    rgcn_layer<<<NBLK, 256, 0, stream>>>(xb, wtp1, b1, off, cnt, sorted_src, h1);
    rgcn_layer<<<NBLK, 256, 0, stream>>>(h1, wtp2, b2, off, cnt, sorted_src, h2);

    // ---- pool + classify ----
    pool_kernel<<<G_GRAPHS, 256, 0, stream>>>(h2, batch, gmean);
    final_kernel<<<G_GRAPHS, HIDF, 0, stream>>>(gmean, lin_w, lin_b, out);

    (void)in_sizes; (void)n_in; (void)out_size; (void)ws_size;
}

// Round 7
// 650.417 us; speedup vs baseline: 1.3229x; 1.3229x over previous
//
#include <hip/hip_runtime.h>

#define N_NODES 50000
#define N_EDGES 1600000
#define R_REL 8
#define G_GRAPHS 64
#define D_INF 128
#define HIDF 128
#define CLSF 10

#define S_SEG (N_NODES * R_REL)   // 400000 (dst, rel) segments
#define KTOT 1152
#define KREL 1024

typedef __attribute__((ext_vector_type(8))) short short8;
typedef __attribute__((ext_vector_type(4))) float floatx4;

__device__ __forceinline__ unsigned short f2bf(float f) {
    unsigned int u = __float_as_uint(f);
    unsigned int r = (u + 0x7fffu + ((u >> 16) & 1u)) >> 16;   // RNE
    return (unsigned short)r;
}
__device__ __forceinline__ float bf2f(unsigned short h) {
    return __uint_as_float(((unsigned int)h) << 16);
}

// ---------------- count edges per (dst, rel) segment ----------------
__global__ void count_kernel(const int* __restrict__ dst, const int* __restrict__ et,
                             int* __restrict__ cnt) {
    int e = blockIdx.x * blockDim.x + threadIdx.x;
    if (e < N_EDGES) {
        atomicAdd(&cnt[dst[e] * R_REL + et[e]], 1);
    }
}

// ---------------- two-level exclusive scan over segment counts ----------------
#define SCAN_BLK 256
#define SCAN_ELEMS 1024
#define NB_SCAN ((S_SEG + SCAN_ELEMS - 1) / SCAN_ELEMS)   // 391

__global__ __launch_bounds__(SCAN_BLK) void scan1_kernel(const int* __restrict__ cnt,
                                                         int* __restrict__ off,
                                                         int* __restrict__ bsum) {
    __shared__ int sd[SCAN_BLK];
    int t = threadIdx.x;
    int base = blockIdx.x * SCAN_ELEMS + t * 4;
    int v[4];
    int tsum = 0;
#pragma unroll
    for (int j = 0; j < 4; j++) {
        v[j] = (base + j < S_SEG) ? cnt[base + j] : 0;
        tsum += v[j];
    }
    sd[t] = tsum;
    __syncthreads();
    for (int d = 1; d < SCAN_BLK; d <<= 1) {
        int x = (t >= d) ? sd[t - d] : 0;
        __syncthreads();
        sd[t] += x;
        __syncthreads();
    }
    int incl = sd[t];
    int run = incl - tsum;
#pragma unroll
    for (int j = 0; j < 4; j++) {
        if (base + j < S_SEG) off[base + j] = run;
        run += v[j];
    }
    if (t == SCAN_BLK - 1) bsum[blockIdx.x] = incl;
}

__global__ __launch_bounds__(512) void scan2_kernel(int* __restrict__ bsum) {
    __shared__ int sd[512];
    int t = threadIdx.x;
    int v = (t < NB_SCAN) ? bsum[t] : 0;
    sd[t] = v;
    __syncthreads();
    for (int d = 1; d < 512; d <<= 1) {
        int x = (t >= d) ? sd[t - d] : 0;
        __syncthreads();
        sd[t] += x;
        __syncthreads();
    }
    if (t < NB_SCAN) bsum[t] = sd[t] - v;
}

// make off[] absolute (add block prefix)
__global__ void absoff_kernel(int* __restrict__ off, const int* __restrict__ bsum) {
    int i = blockIdx.x * blockDim.x + threadIdx.x;
    if (i < S_SEG) off[i] += bsum[i >> 10];
}

// ---------------- bin edges into segment-sorted src list ----------------
__global__ void bin_kernel(const int* __restrict__ src,
                           const int* __restrict__ dst,
                           const int* __restrict__ et,
                           const int* __restrict__ off,
                           int* __restrict__ cursor,
                           int* __restrict__ sorted_src) {
    int e = blockIdx.x * blockDim.x + threadIdx.x;
    if (e < N_EDGES) {
        int seg = dst[e] * R_REL + et[e];
        int pos = atomicAdd(&cursor[seg], 1);
        sorted_src[off[seg] + pos] = src[e];
    }
}

// ---------------- convert x fp32 -> bf16 compact [N,128] ----------------
__global__ void convx_kernel(const float* __restrict__ x, unsigned short* __restrict__ xb) {
    int idx = blockIdx.x * blockDim.x + threadIdx.x;
    if (idx < N_NODES * D_INF) xb[idx] = f2bf(x[idx]);
}

// ---------------- build transposed bf16 weights wt[128][1152]: [col][k] ----------
// wt[c][k] = (k<1024 ? Wf[k][c] : root[k-1024][c])
__global__ __launch_bounds__(256) void convw_kernel(const float* __restrict__ Wf,
                                                    const float* __restrict__ root,
                                                    unsigned short* __restrict__ wt) {
    __shared__ float t[16][17];
    int k0 = blockIdx.x * 16, c0 = blockIdx.y * 16;
    int tx = threadIdx.x & 15, ty = threadIdx.x >> 4;
    int k = k0 + ty, c = c0 + tx;
    float v = (k < KREL) ? Wf[(size_t)k * HIDF + c] : root[(size_t)(k - KREL) * HIDF + c];
    t[ty][tx] = v;
    __syncthreads();
    wt[(size_t)(c0 + ty) * KTOT + k0 + tx] = f2bf(t[tx][ty]);
}

// ---------------- gather-aggregate: per-segment mean, no atomics ----------------
// One 32-lane group per segment; lane c covers 4 bf16 channels. Edge loop
// unrolled x4: 4 independent idx loads then 4 independent row loads per round.
__global__ __launch_bounds__(256) void agg_kernel(const unsigned short* __restrict__ feat,  // [N,128]
                                                  const int* __restrict__ sorted_src,
                                                  const int* __restrict__ off,    // absolute
                                                  const int* __restrict__ cnt,
                                                  unsigned short* __restrict__ meanb) { // [N,1024]
    int g = blockIdx.x * 8 + (threadIdx.x >> 5);
    if (g >= S_SEG) return;
    int c = threadIdx.x & 31;
    int n = cnt[g];
    int beg = off[g];
    float a0 = 0.f, a1 = 0.f, a2 = 0.f, a3 = 0.f;
    int i = 0;
    for (; i + 4 <= n; i += 4) {
        int i0 = sorted_src[beg + i + 0];
        int i1 = sorted_src[beg + i + 1];
        int i2 = sorted_src[beg + i + 2];
        int i3 = sorted_src[beg + i + 3];
        ushort4 v0 = *(const ushort4*)(feat + (size_t)i0 * HIDF + c * 4);
        ushort4 v1 = *(const ushort4*)(feat + (size_t)i1 * HIDF + c * 4);
        ushort4 v2 = *(const ushort4*)(feat + (size_t)i2 * HIDF + c * 4);
        ushort4 v3 = *(const ushort4*)(feat + (size_t)i3 * HIDF + c * 4);
        a0 += bf2f(v0.x) + bf2f(v1.x) + bf2f(v2.x) + bf2f(v3.x);
        a1 += bf2f(v0.y) + bf2f(v1.y) + bf2f(v2.y) + bf2f(v3.y);
        a2 += bf2f(v0.z) + bf2f(v1.z) + bf2f(v2.z) + bf2f(v3.z);
        a3 += bf2f(v0.w) + bf2f(v1.w) + bf2f(v2.w) + bf2f(v3.w);
    }
    for (; i < n; i++) {
        int ii = sorted_src[beg + i];
        ushort4 v = *(const ushort4*)(feat + (size_t)ii * HIDF + c * 4);
        a0 += bf2f(v.x); a1 += bf2f(v.y); a2 += bf2f(v.z); a3 += bf2f(v.w);
    }
    float inv = 1.0f / (float)max(n, 1);
    ushort4 o;
    o.x = f2bf(a0 * inv); o.y = f2bf(a1 * inv);
    o.z = f2bf(a2 * inv); o.w = f2bf(a3 * inv);
    int node = g >> 3, rel = g & 7;
    *(ushort4*)(meanb + (size_t)node * KREL + rel * HIDF + c * 4) = o;
}

// ---------------- MFMA bf16 fused RGCN layer GEMM (validated round 4) -------
// out[row][col] = relu( sum_k A[row][k] * wt[col][k] + bias[col] ), bf16 out.
// A[row][k] = meanb[row][k] for k<1024, hin[row][k-1024] for k>=1024.
// 128x128 tile, BK=32, 4 waves: wave handles 32 rows x 128 cols = 2x8 frags.
__global__ __launch_bounds__(256) void gemm_mfma(
    const unsigned short* __restrict__ meanb,  // [N, 1024] bf16
    const unsigned short* __restrict__ hin,    // [N, 128] bf16
    const unsigned short* __restrict__ wt,     // [128, 1152] bf16 (transposed weights)
    const float* __restrict__ bias,            // [128] fp32
    unsigned short* __restrict__ hout)         // [N, 128] bf16
{
    __shared__ __align__(16) unsigned short Alds[128][40];   // pad 32->40
    __shared__ __align__(16) unsigned short Blds[128][40];

    const int tx = threadIdx.x;
    const int wave = tx >> 6, lane = tx & 63;
    const int quad = lane >> 4, lq = lane & 15;
    const int row0 = blockIdx.x * 128;

    floatx4 acc[2][8];
#pragma unroll
    for (int i = 0; i < 2; i++)
#pragma unroll
        for (int j = 0; j < 8; j++) acc[i][j] = (floatx4){0.f, 0.f, 0.f, 0.f};

    for (int k0 = 0; k0 < KTOT; k0 += 32) {
        // stage A (128 rows x 32 k) and B (128 cols x 32 k): 2 passes x 256 thr x 16B
#pragma unroll
        for (int p = 0; p < 2; p++) {
            int idx = tx + p * 256;
            int r = idx >> 2, ch = idx & 3;
            int gr = row0 + r;
            uint4 va = make_uint4(0u, 0u, 0u, 0u);
            if (gr < N_NODES) {
                if (k0 < KREL)
                    va = *(const uint4*)(meanb + (size_t)gr * KREL + k0 + ch * 8);
                else
                    va = *(const uint4*)(hin + (size_t)gr * HIDF + (k0 - KREL) + ch * 8);
            }
            *(uint4*)(&Alds[r][ch * 8]) = va;
            uint4 vb = *(const uint4*)(wt + (size_t)r * KTOT + k0 + ch * 8);
            *(uint4*)(&Blds[r][ch * 8]) = vb;
        }
        __syncthreads();

        short8 af[2], bfr[8];
#pragma unroll
        for (int i = 0; i < 2; i++)
            af[i] = *(const short8*)(&Alds[wave * 32 + i * 16 + lq][quad * 8]);
#pragma unroll
        for (int j = 0; j < 8; j++)
            bfr[j] = *(const short8*)(&Blds[j * 16 + lq][quad * 8]);
#pragma unroll
        for (int i = 0; i < 2; i++)
#pragma unroll
            for (int j = 0; j < 8; j++)
                acc[i][j] = __builtin_amdgcn_mfma_f32_16x16x32_bf16(af[i], bfr[j], acc[i][j], 0, 0, 0);
        __syncthreads();
    }

    // epilogue: C/D layout col=lane&15, row=quad*4+reg
#pragma unroll
    for (int i = 0; i < 2; i++) {
#pragma unroll
        for (int j = 0; j < 8; j++) {
            int col = j * 16 + lq;
            float b = bias[col];
#pragma unroll
            for (int r = 0; r < 4; r++) {
                int row = row0 + wave * 32 + i * 16 + quad * 4 + r;
                if (row < N_NODES) {
                    float v = fmaxf(acc[i][j][r] + b, 0.0f);
                    hout[(size_t)row * HIDF + col] = f2bf(v);
                }
            }
        }
    }
}

// ---------------- global mean pool (batch sorted -> per-graph ranges) ----------
__global__ __launch_bounds__(256) void pool_kernel(const unsigned short* __restrict__ h,
                                                   const int* __restrict__ batch,
                                                   float* __restrict__ gmean) {
    int g = blockIdx.x;
    int lo, hi;
    {
        int l = 0, r = N_NODES;
        while (l < r) { int m = (l + r) >> 1; if (batch[m] < g) l = m + 1; else r = m; }
        lo = l;
        l = lo; r = N_NODES;
        while (l < r) { int m = (l + r) >> 1; if (batch[m] < g + 1) l = m + 1; else r = m; }
        hi = l;
    }
    int t = threadIdx.x;
    int c = t & 127;
    int half = t >> 7;
    float s = 0.0f;
    for (int n = lo + half; n < hi; n += 2) {
        s += bf2f(h[(size_t)n * HIDF + c]);
    }
    __shared__ float red[256];
    red[t] = s;
    __syncthreads();
    if (t < 128) {
        float tot = red[t] + red[t + 128];
        int n = hi - lo;
        gmean[g * HIDF + t] = tot / (float)max(n, 1);
    }
}

// ---------------- final linear ----------------
__global__ void final_kernel(const float* __restrict__ gmean,
                             const float* __restrict__ lin_w,  // [128, 10]
                             const float* __restrict__ lin_b,  // [10]
                             float* __restrict__ out) {        // [64, 10]
    __shared__ float gl[HIDF];
    int g = blockIdx.x;
    int hh = threadIdx.x;
    gl[hh] = gmean[g * HIDF + hh];
    __syncthreads();
    if (hh < CLSF) {
        float s = lin_b[hh];
#pragma unroll 16
        for (int d = 0; d < HIDF; d++) s += gl[d] * lin_w[d * CLSF + hh];
        out[g * CLSF + hh] = s;
    }
}

extern "C" void kernel_launch(void* const* d_in, const int* in_sizes, int n_in,
                              void* d_out, int out_size, void* d_ws, size_t ws_size,
                              hipStream_t stream) {
    const float* x     = (const float*)d_in[0];
    const int*   ei    = (const int*)d_in[1];
    const int*   et    = (const int*)d_in[2];
    const int*   batch = (const int*)d_in[3];
    const float* W1    = (const float*)d_in[4];
    const float* root1 = (const float*)d_in[5];
    const float* b1    = (const float*)d_in[6];
    const float* W2    = (const float*)d_in[7];
    const float* root2 = (const float*)d_in[8];
    const float* b2    = (const float*)d_in[9];
    const float* lin_w = (const float*)d_in[10];
    const float* lin_b = (const float*)d_in[11];
    float* out = (float*)d_out;

    const int* src = ei;            // edge_index[0]
    const int* dst = ei + N_EDGES;  // edge_index[1]

    char* ws = (char*)d_ws;
    unsigned short* xb   = (unsigned short*)ws; ws += (size_t)N_NODES * HIDF * 2;  // 12.8 MB
    unsigned short* h1   = (unsigned short*)ws; ws += (size_t)N_NODES * HIDF * 2;  // 12.8 MB
    unsigned short* h2   = (unsigned short*)ws; ws += (size_t)N_NODES * HIDF * 2;  // 12.8 MB
    unsigned short* meanb= (unsigned short*)ws; ws += (size_t)N_NODES * KREL * 2;  // 102.4 MB
    unsigned short* wt1  = (unsigned short*)ws; ws += (size_t)HIDF * KTOT * 2;     // 288 KB
    unsigned short* wt2  = (unsigned short*)ws; ws += (size_t)HIDF * KTOT * 2;
    int*   cnt    = (int*)ws;   ws += (size_t)S_SEG * 4;
    int*   off    = (int*)ws;   ws += (size_t)S_SEG * 4;
    int*   bsum   = (int*)ws;   ws += 512 * 4;
    int*   cursor = (int*)ws;   ws += (size_t)S_SEG * 4;
    int*   sorted_src = (int*)ws; ws += (size_t)N_EDGES * 4;
    float* gmean  = (float*)ws; ws += (size_t)G_GRAPHS * HIDF * 4;

    hipMemsetAsync(cnt, 0, (size_t)S_SEG * 4, stream);
    hipMemsetAsync(cursor, 0, (size_t)S_SEG * 4, stream);

    // ---- counting sort of edges by (dst, rel) segment ----
    count_kernel<<<(N_EDGES + 255) / 256, 256, 0, stream>>>(dst, et, cnt);
    scan1_kernel<<<NB_SCAN, SCAN_BLK, 0, stream>>>(cnt, off, bsum);
    scan2_kernel<<<1, 512, 0, stream>>>(bsum);
    absoff_kernel<<<(S_SEG + 255) / 256, 256, 0, stream>>>(off, bsum);
    bin_kernel<<<(N_EDGES + 255) / 256, 256, 0, stream>>>(src, dst, et, off,
                                                          cursor, sorted_src);

    // ---- bf16 conversions ----
    convx_kernel<<<(N_NODES * D_INF + 255) / 256, 256, 0, stream>>>(x, xb);
    convw_kernel<<<dim3(KTOT / 16, HIDF / 16), 256, 0, stream>>>(W1, root1, wt1);
    convw_kernel<<<dim3(KTOT / 16, HIDF / 16), 256, 0, stream>>>(W2, root2, wt2);

    // ---- layer 1 ----
    agg_kernel<<<(S_SEG + 7) / 8, 256, 0, stream>>>(xb, sorted_src, off, cnt, meanb);
    gemm_mfma<<<(N_NODES + 127) / 128, 256, 0, stream>>>(meanb, xb, wt1, b1, h1);

    // ---- layer 2 ----
    agg_kernel<<<(S_SEG + 7) / 8, 256, 0, stream>>>(h1, sorted_src, off, cnt, meanb);
    gemm_mfma<<<(N_NODES + 127) / 128, 256, 0, stream>>>(meanb, h1, wt2, b2, h2);

    // ---- pool + classify ----
    pool_kernel<<<G_GRAPHS, 256, 0, stream>>>(h2, batch, gmean);
    final_kernel<<<G_GRAPHS, HIDF, 0, stream>>>(gmean, lin_w, lin_b, out);

    (void)in_sizes; (void)n_in; (void)out_size; (void)ws_size;
}

// Round 8
// 557.018 us; speedup vs baseline: 1.5447x; 1.1677x over previous
//
#include <hip/hip_runtime.h>

#define N_NODES 50000
#define N_EDGES 1600000
#define R_REL 8
#define G_GRAPHS 64
#define D_INF 128
#define HIDF 128
#define CLSF 10

#define S_SEG (N_NODES * R_REL)   // 400000 (dst, rel) segments
#define KTOT 1152
#define KREL 1024
#define PCHUNK 16                 // pool stage-1 chunks per graph

typedef __attribute__((ext_vector_type(8))) short short8;
typedef __attribute__((ext_vector_type(4))) float floatx4;

__device__ __forceinline__ unsigned short f2bf(float f) {
    unsigned int u = __float_as_uint(f);
    unsigned int r = (u + 0x7fffu + ((u >> 16) & 1u)) >> 16;   // RNE
    return (unsigned short)r;
}
__device__ __forceinline__ float bf2f(unsigned short h) {
    return __uint_as_float(((unsigned int)h) << 16);
}

// ---------------- count edges per (dst, rel) segment ----------------
__global__ void count_kernel(const int* __restrict__ dst, const int* __restrict__ et,
                             int* __restrict__ cnt) {
    int e = blockIdx.x * blockDim.x + threadIdx.x;
    if (e < N_EDGES) {
        atomicAdd(&cnt[dst[e] * R_REL + et[e]], 1);
    }
}

// ---------------- two-level exclusive scan over segment counts ----------------
#define SCAN_BLK 256
#define SCAN_ELEMS 1024
#define NB_SCAN ((S_SEG + SCAN_ELEMS - 1) / SCAN_ELEMS)   // 391

__global__ __launch_bounds__(SCAN_BLK) void scan1_kernel(const int* __restrict__ cnt,
                                                         int* __restrict__ off,
                                                         int* __restrict__ bsum) {
    __shared__ int sd[SCAN_BLK];
    int t = threadIdx.x;
    int base = blockIdx.x * SCAN_ELEMS + t * 4;
    int v[4];
    int tsum = 0;
#pragma unroll
    for (int j = 0; j < 4; j++) {
        v[j] = (base + j < S_SEG) ? cnt[base + j] : 0;
        tsum += v[j];
    }
    sd[t] = tsum;
    __syncthreads();
    for (int d = 1; d < SCAN_BLK; d <<= 1) {
        int x = (t >= d) ? sd[t - d] : 0;
        __syncthreads();
        sd[t] += x;
        __syncthreads();
    }
    int incl = sd[t];
    int run = incl - tsum;
#pragma unroll
    for (int j = 0; j < 4; j++) {
        if (base + j < S_SEG) off[base + j] = run;
        run += v[j];
    }
    if (t == SCAN_BLK - 1) bsum[blockIdx.x] = incl;
}

__global__ __launch_bounds__(512) void scan2_kernel(int* __restrict__ bsum) {
    __shared__ int sd[512];
    int t = threadIdx.x;
    int v = (t < NB_SCAN) ? bsum[t] : 0;
    sd[t] = v;
    __syncthreads();
    for (int d = 1; d < 512; d <<= 1) {
        int x = (t >= d) ? sd[t - d] : 0;
        __syncthreads();
        sd[t] += x;
        __syncthreads();
    }
    if (t < NB_SCAN) bsum[t] = sd[t] - v;
}

// make off[] absolute (add block prefix)
__global__ void absoff_kernel(int* __restrict__ off, const int* __restrict__ bsum) {
    int i = blockIdx.x * blockDim.x + threadIdx.x;
    if (i < S_SEG) off[i] += bsum[i >> 10];
}

// ---------------- bin edges into segment-sorted src list ----------------
__global__ void bin_kernel(const int* __restrict__ src,
                           const int* __restrict__ dst,
                           const int* __restrict__ et,
                           const int* __restrict__ off,
                           int* __restrict__ cursor,
                           int* __restrict__ sorted_src) {
    int e = blockIdx.x * blockDim.x + threadIdx.x;
    if (e < N_EDGES) {
        int seg = dst[e] * R_REL + et[e];
        int pos = atomicAdd(&cursor[seg], 1);
        sorted_src[off[seg] + pos] = src[e];
    }
}

// ---------------- convert x fp32 -> bf16 compact [N,128] ----------------
__global__ void convx_kernel(const float* __restrict__ x, unsigned short* __restrict__ xb) {
    int idx = blockIdx.x * blockDim.x + threadIdx.x;
    if (idx < N_NODES * D_INF) xb[idx] = f2bf(x[idx]);
}

// ---------------- build transposed bf16 weights wt[128][1152]: [col][k] ----------
__global__ __launch_bounds__(256) void convw_kernel(const float* __restrict__ Wf,
                                                    const float* __restrict__ root,
                                                    unsigned short* __restrict__ wt) {
    __shared__ float t[16][17];
    int k0 = blockIdx.x * 16, c0 = blockIdx.y * 16;
    int tx = threadIdx.x & 15, ty = threadIdx.x >> 4;
    int k = k0 + ty, c = c0 + tx;
    float v = (k < KREL) ? Wf[(size_t)k * HIDF + c] : root[(size_t)(k - KREL) * HIDF + c];
    t[ty][tx] = v;
    __syncthreads();
    wt[(size_t)(c0 + ty) * KTOT + k0 + tx] = f2bf(t[tx][ty]);
}

// ---------------- gather-aggregate: per-segment mean, no atomics ----------------
__global__ __launch_bounds__(256) void agg_kernel(const unsigned short* __restrict__ feat,  // [N,128]
                                                  const int* __restrict__ sorted_src,
                                                  const int* __restrict__ off,    // absolute
                                                  const int* __restrict__ cnt,
                                                  unsigned short* __restrict__ meanb) { // [N,1024]
    int g = blockIdx.x * 8 + (threadIdx.x >> 5);
    if (g >= S_SEG) return;
    int c = threadIdx.x & 31;
    int n = cnt[g];
    int beg = off[g];
    float a0 = 0.f, a1 = 0.f, a2 = 0.f, a3 = 0.f;
    int i = 0;
    for (; i + 4 <= n; i += 4) {
        int i0 = sorted_src[beg + i + 0];
        int i1 = sorted_src[beg + i + 1];
        int i2 = sorted_src[beg + i + 2];
        int i3 = sorted_src[beg + i + 3];
        ushort4 v0 = *(const ushort4*)(feat + (size_t)i0 * HIDF + c * 4);
        ushort4 v1 = *(const ushort4*)(feat + (size_t)i1 * HIDF + c * 4);
        ushort4 v2 = *(const ushort4*)(feat + (size_t)i2 * HIDF + c * 4);
        ushort4 v3 = *(const ushort4*)(feat + (size_t)i3 * HIDF + c * 4);
        a0 += bf2f(v0.x) + bf2f(v1.x) + bf2f(v2.x) + bf2f(v3.x);
        a1 += bf2f(v0.y) + bf2f(v1.y) + bf2f(v2.y) + bf2f(v3.y);
        a2 += bf2f(v0.z) + bf2f(v1.z) + bf2f(v2.z) + bf2f(v3.z);
        a3 += bf2f(v0.w) + bf2f(v1.w) + bf2f(v2.w) + bf2f(v3.w);
    }
    for (; i < n; i++) {
        int ii = sorted_src[beg + i];
        ushort4 v = *(const ushort4*)(feat + (size_t)ii * HIDF + c * 4);
        a0 += bf2f(v.x); a1 += bf2f(v.y); a2 += bf2f(v.z); a3 += bf2f(v.w);
    }
    float inv = 1.0f / (float)max(n, 1);
    ushort4 o;
    o.x = f2bf(a0 * inv); o.y = f2bf(a1 * inv);
    o.z = f2bf(a2 * inv); o.w = f2bf(a3 * inv);
    int node = g >> 3, rel = g & 7;
    *(ushort4*)(meanb + (size_t)node * KREL + rel * HIDF + c * 4) = o;
}

// ---------------- MFMA bf16 fused RGCN layer GEMM ----------------
__global__ __launch_bounds__(256) void gemm_mfma(
    const unsigned short* __restrict__ meanb,  // [N, 1024] bf16
    const unsigned short* __restrict__ hin,    // [N, 128] bf16
    const unsigned short* __restrict__ wt,     // [128, 1152] bf16 (transposed weights)
    const float* __restrict__ bias,            // [128] fp32
    unsigned short* __restrict__ hout)         // [N, 128] bf16
{
    __shared__ __align__(16) unsigned short Alds[128][40];   // pad 32->40
    __shared__ __align__(16) unsigned short Blds[128][40];

    const int tx = threadIdx.x;
    const int wave = tx >> 6, lane = tx & 63;
    const int quad = lane >> 4, lq = lane & 15;
    const int row0 = blockIdx.x * 128;

    floatx4 acc[2][8];
#pragma unroll
    for (int i = 0; i < 2; i++)
#pragma unroll
        for (int j = 0; j < 8; j++) acc[i][j] = (floatx4){0.f, 0.f, 0.f, 0.f};

    for (int k0 = 0; k0 < KTOT; k0 += 32) {
#pragma unroll
        for (int p = 0; p < 2; p++) {
            int idx = tx + p * 256;
            int r = idx >> 2, ch = idx & 3;
            int gr = row0 + r;
            uint4 va = make_uint4(0u, 0u, 0u, 0u);
            if (gr < N_NODES) {
                if (k0 < KREL)
                    va = *(const uint4*)(meanb + (size_t)gr * KREL + k0 + ch * 8);
                else
                    va = *(const uint4*)(hin + (size_t)gr * HIDF + (k0 - KREL) + ch * 8);
            }
            *(uint4*)(&Alds[r][ch * 8]) = va;
            uint4 vb = *(const uint4*)(wt + (size_t)r * KTOT + k0 + ch * 8);
            *(uint4*)(&Blds[r][ch * 8]) = vb;
        }
        __syncthreads();

        short8 af[2], bfr[8];
#pragma unroll
        for (int i = 0; i < 2; i++)
            af[i] = *(const short8*)(&Alds[wave * 32 + i * 16 + lq][quad * 8]);
#pragma unroll
        for (int j = 0; j < 8; j++)
            bfr[j] = *(const short8*)(&Blds[j * 16 + lq][quad * 8]);
#pragma unroll
        for (int i = 0; i < 2; i++)
#pragma unroll
            for (int j = 0; j < 8; j++)
                acc[i][j] = __builtin_amdgcn_mfma_f32_16x16x32_bf16(af[i], bfr[j], acc[i][j], 0, 0, 0);
        __syncthreads();
    }

#pragma unroll
    for (int i = 0; i < 2; i++) {
#pragma unroll
        for (int j = 0; j < 8; j++) {
            int col = j * 16 + lq;
            float b = bias[col];
#pragma unroll
            for (int r = 0; r < 4; r++) {
                int row = row0 + wave * 32 + i * 16 + quad * 4 + r;
                if (row < N_NODES) {
                    float v = fmaxf(acc[i][j][r] + b, 0.0f);
                    hout[(size_t)row * HIDF + col] = f2bf(v);
                }
            }
        }
    }
}

// ---------------- global mean pool, two-stage, no atomics ----------------
// Stage 1: grid = (G_GRAPHS, PCHUNK). Block (g, p) sums rows lo+p, lo+p+PCHUNK, ...
// Thread layout: lane = 4 channels (ushort4), 32 lanes per row, 8 rows in flight.
__global__ __launch_bounds__(256) void pool1_kernel(const unsigned short* __restrict__ h,
                                                    const int* __restrict__ batch,
                                                    float* __restrict__ partial) {  // [G][PCHUNK][128]
    int g = blockIdx.x;
    int p = blockIdx.y;
    int lo, hi;
    {
        int l = 0, r = N_NODES;
        while (l < r) { int m = (l + r) >> 1; if (batch[m] < g) l = m + 1; else r = m; }
        lo = l;
        l = lo; r = N_NODES;
        while (l < r) { int m = (l + r) >> 1; if (batch[m] < g + 1) l = m + 1; else r = m; }
        hi = l;
    }
    int t = threadIdx.x;
    int rowlane = t >> 5;          // 0..7: row slot
    int c4 = t & 31;               // channel group (4 ch)
    float a0 = 0.f, a1 = 0.f, a2 = 0.f, a3 = 0.f;
    for (int n = lo + p + rowlane * PCHUNK; n < hi; n += 8 * PCHUNK) {
        ushort4 v = *(const ushort4*)(h + (size_t)n * HIDF + c4 * 4);
        a0 += bf2f(v.x); a1 += bf2f(v.y); a2 += bf2f(v.z); a3 += bf2f(v.w);
    }
    // reduce 8 row slots in LDS
    __shared__ float red[8][128];
    if (rowlane == 0) {
        red[0][c4 * 4 + 0] = a0; red[0][c4 * 4 + 1] = a1;
        red[0][c4 * 4 + 2] = a2; red[0][c4 * 4 + 3] = a3;
    }
    __syncthreads();
    for (int s = 1; s < 8; s++) {
        if (rowlane == s) {
            red[0][c4 * 4 + 0] += a0; red[0][c4 * 4 + 1] += a1;
            red[0][c4 * 4 + 2] += a2; red[0][c4 * 4 + 3] += a3;
        }
        __syncthreads();
    }
    if (t < 128) partial[((size_t)g * PCHUNK + p) * 128 + t] = red[0][t];
}

// Stage 2: one block per graph, sum PCHUNK partials, divide by count.
__global__ __launch_bounds__(128) void pool2_kernel(const float* __restrict__ partial,
                                                    const int* __restrict__ batch,
                                                    float* __restrict__ gmean) {
    int g = blockIdx.x;
    int lo, hi;
    {
        int l = 0, r = N_NODES;
        while (l < r) { int m = (l + r) >> 1; if (batch[m] < g) l = m + 1; else r = m; }
        lo = l;
        l = lo; r = N_NODES;
        while (l < r) { int m = (l + r) >> 1; if (batch[m] < g + 1) l = m + 1; else r = m; }
        hi = l;
    }
    int t = threadIdx.x;
    float s = 0.f;
#pragma unroll
    for (int p = 0; p < PCHUNK; p++)
        s += partial[((size_t)g * PCHUNK + p) * 128 + t];
    gmean[g * HIDF + t] = s / (float)max(hi - lo, 1);
}

// ---------------- final linear ----------------
__global__ void final_kernel(const float* __restrict__ gmean,
                             const float* __restrict__ lin_w,  // [128, 10]
                             const float* __restrict__ lin_b,  // [10]
                             float* __restrict__ out) {        // [64, 10]
    __shared__ float gl[HIDF];
    int g = blockIdx.x;
    int hh = threadIdx.x;
    gl[hh] = gmean[g * HIDF + hh];
    __syncthreads();
    if (hh < CLSF) {
        float s = lin_b[hh];
#pragma unroll 16
        for (int d = 0; d < HIDF; d++) s += gl[d] * lin_w[d * CLSF + hh];
        out[g * CLSF + hh] = s;
    }
}

extern "C" void kernel_launch(void* const* d_in, const int* in_sizes, int n_in,
                              void* d_out, int out_size, void* d_ws, size_t ws_size,
                              hipStream_t stream) {
    const float* x     = (const float*)d_in[0];
    const int*   ei    = (const int*)d_in[1];
    const int*   et    = (const int*)d_in[2];
    const int*   batch = (const int*)d_in[3];
    const float* W1    = (const float*)d_in[4];
    const float* root1 = (const float*)d_in[5];
    const float* b1    = (const float*)d_in[6];
    const float* W2    = (const float*)d_in[7];
    const float* root2 = (const float*)d_in[8];
    const float* b2    = (const float*)d_in[9];
    const float* lin_w = (const float*)d_in[10];
    const float* lin_b = (const float*)d_in[11];
    float* out = (float*)d_out;

    const int* src = ei;            // edge_index[0]
    const int* dst = ei + N_EDGES;  // edge_index[1]

    char* ws = (char*)d_ws;
    unsigned short* xb   = (unsigned short*)ws; ws += (size_t)N_NODES * HIDF * 2;  // 12.8 MB
    unsigned short* h1   = (unsigned short*)ws; ws += (size_t)N_NODES * HIDF * 2;  // 12.8 MB
    unsigned short* h2   = (unsigned short*)ws; ws += (size_t)N_NODES * HIDF * 2;  // 12.8 MB
    unsigned short* meanb= (unsigned short*)ws; ws += (size_t)N_NODES * KREL * 2;  // 102.4 MB
    unsigned short* wt1  = (unsigned short*)ws; ws += (size_t)HIDF * KTOT * 2;     // 288 KB
    unsigned short* wt2  = (unsigned short*)ws; ws += (size_t)HIDF * KTOT * 2;
    int*   cnt    = (int*)ws;   ws += (size_t)S_SEG * 4;
    int*   off    = (int*)ws;   ws += (size_t)S_SEG * 4;
    int*   bsum   = (int*)ws;   ws += 512 * 4;
    int*   cursor = (int*)ws;   ws += (size_t)S_SEG * 4;
    int*   sorted_src = (int*)ws; ws += (size_t)N_EDGES * 4;
    float* partial = (float*)ws; ws += (size_t)G_GRAPHS * PCHUNK * 128 * 4;        // 512 KB
    float* gmean  = (float*)ws; ws += (size_t)G_GRAPHS * HIDF * 4;

    hipMemsetAsync(cnt, 0, (size_t)S_SEG * 4, stream);
    hipMemsetAsync(cursor, 0, (size_t)S_SEG * 4, stream);

    // ---- counting sort of edges by (dst, rel) segment ----
    count_kernel<<<(N_EDGES + 255) / 256, 256, 0, stream>>>(dst, et, cnt);
    scan1_kernel<<<NB_SCAN, SCAN_BLK, 0, stream>>>(cnt, off, bsum);
    scan2_kernel<<<1, 512, 0, stream>>>(bsum);
    absoff_kernel<<<(S_SEG + 255) / 256, 256, 0, stream>>>(off, bsum);
    bin_kernel<<<(N_EDGES + 255) / 256, 256, 0, stream>>>(src, dst, et, off,
                                                          cursor, sorted_src);

    // ---- bf16 conversions ----
    convx_kernel<<<(N_NODES * D_INF + 255) / 256, 256, 0, stream>>>(x, xb);
    convw_kernel<<<dim3(KTOT / 16, HIDF / 16), 256, 0, stream>>>(W1, root1, wt1);
    convw_kernel<<<dim3(KTOT / 16, HIDF / 16), 256, 0, stream>>>(W2, root2, wt2);

    // ---- layer 1 ----
    agg_kernel<<<(S_SEG + 7) / 8, 256, 0, stream>>>(xb, sorted_src, off, cnt, meanb);
    gemm_mfma<<<(N_NODES + 127) / 128, 256, 0, stream>>>(meanb, xb, wt1, b1, h1);

    // ---- layer 2 ----
    agg_kernel<<<(S_SEG + 7) / 8, 256, 0, stream>>>(h1, sorted_src, off, cnt, meanb);
    gemm_mfma<<<(N_NODES + 127) / 128, 256, 0, stream>>>(meanb, h1, wt2, b2, h2);

    // ---- pool (two-stage, no atomics) + classify ----
    pool1_kernel<<<dim3(G_GRAPHS, PCHUNK), 256, 0, stream>>>(h2, batch, partial);
    pool2_kernel<<<G_GRAPHS, 128, 0, stream>>>(partial, batch, gmean);
    final_kernel<<<G_GRAPHS, HIDF, 0, stream>>>(gmean, lin_w, lin_b, out);

    (void)in_sizes; (void)n_in; (void)out_size; (void)ws_size;
}